// Round 10
// baseline (758.499 us; speedup 1.0000x reference)
//
#include <hip/hip_runtime.h>
#include <hip/hip_cooperative_groups.h>

namespace cg = cooperative_groups;

#define N_NODES 50000
#define N_EDGES 800000
#define CDIM 100
#define HDIM 200
#define ODIM 100

#define BLK 256
#define PITCH_U 64   // node rows: 128 bf16 = 64 uints = 256 B
#define VCHUNKS 1024 // virtual scan chunks (fixed, grid-independent)
#define CHUNK 49     // nodes per chunk: 1024*49 >= 50000

typedef __bf16 bf16x8 __attribute__((ext_vector_type(8)));
typedef float f32x4 __attribute__((ext_vector_type(4)));
typedef unsigned short ushort_t;

__device__ __forceinline__ unsigned f2bf(float f) {
    unsigned u = __float_as_uint(f);
    u = (u + 0x7FFFu + ((u >> 16) & 1u)) >> 16;
    return u;  // low 16 bits valid
}
__device__ __forceinline__ float bflo(unsigned u) { return __uint_as_float(u << 16); }
__device__ __forceinline__ float bfhi(unsigned u) { return __uint_as_float(u & 0xFFFF0000u); }

// ---- CSR aggregation body (proven R6/R8 structure: 8-deep unconditional ILP) ----
template <bool BIAS_RELU>
__device__ __forceinline__ void agg_node(int n, int lane, const unsigned* __restrict__ hb,
                                         const int* __restrict__ ssrc,
                                         const int* __restrict__ off,
                                         const float* __restrict__ bias,
                                         unsigned* __restrict__ outb,
                                         float2* __restrict__ outf) {
    int s0 = off[n], s1 = off[n + 1];
    float2 a0 = {0.f, 0.f}, a1 = {0.f, 0.f}, a2 = {0.f, 0.f}, a3 = {0.f, 0.f};
    int j = s0;
    for (; j + 7 < s1; j += 8) {
        int r0 = ssrc[j],     r1 = ssrc[j + 1], r2 = ssrc[j + 2], r3 = ssrc[j + 3];
        int r4 = ssrc[j + 4], r5 = ssrc[j + 5], r6 = ssrc[j + 6], r7 = ssrc[j + 7];
        unsigned u0 = hb[(size_t)r0 * PITCH_U + lane];
        unsigned u1 = hb[(size_t)r1 * PITCH_U + lane];
        unsigned u2 = hb[(size_t)r2 * PITCH_U + lane];
        unsigned u3 = hb[(size_t)r3 * PITCH_U + lane];
        unsigned u4 = hb[(size_t)r4 * PITCH_U + lane];
        unsigned u5 = hb[(size_t)r5 * PITCH_U + lane];
        unsigned u6 = hb[(size_t)r6 * PITCH_U + lane];
        unsigned u7 = hb[(size_t)r7 * PITCH_U + lane];
        a0.x += bflo(u0); a0.y += bfhi(u0);
        a1.x += bflo(u1); a1.y += bfhi(u1);
        a2.x += bflo(u2); a2.y += bfhi(u2);
        a3.x += bflo(u3); a3.y += bfhi(u3);
        a0.x += bflo(u4); a0.y += bfhi(u4);
        a1.x += bflo(u5); a1.y += bfhi(u5);
        a2.x += bflo(u6); a2.y += bfhi(u6);
        a3.x += bflo(u7); a3.y += bfhi(u7);
    }
    for (; j + 3 < s1; j += 4) {
        int r0 = ssrc[j], r1 = ssrc[j + 1], r2 = ssrc[j + 2], r3 = ssrc[j + 3];
        unsigned u0 = hb[(size_t)r0 * PITCH_U + lane];
        unsigned u1 = hb[(size_t)r1 * PITCH_U + lane];
        unsigned u2 = hb[(size_t)r2 * PITCH_U + lane];
        unsigned u3 = hb[(size_t)r3 * PITCH_U + lane];
        a0.x += bflo(u0); a0.y += bfhi(u0);
        a1.x += bflo(u1); a1.y += bfhi(u1);
        a2.x += bflo(u2); a2.y += bfhi(u2);
        a3.x += bflo(u3); a3.y += bfhi(u3);
    }
    {
        int rem = s1 - j;
        if (rem > 0) { unsigned u = hb[(size_t)ssrc[j] * PITCH_U + lane];     a0.x += bflo(u); a0.y += bfhi(u); }
        if (rem > 1) { unsigned u = hb[(size_t)ssrc[j + 1] * PITCH_U + lane]; a1.x += bflo(u); a1.y += bfhi(u); }
        if (rem > 2) { unsigned u = hb[(size_t)ssrc[j + 2] * PITCH_U + lane]; a2.x += bflo(u); a2.y += bfhi(u); }
    }
    float rx = (a0.x + a1.x) + (a2.x + a3.x);
    float ry = (a0.y + a1.y) + (a2.y + a3.y);
    if (BIAS_RELU) {
        if (lane < 50) {
            rx = fmaxf(rx + bias[2 * lane], 0.f);
            ry = fmaxf(ry + bias[2 * lane + 1], 0.f);
            outf[(size_t)n * 50 + lane] = make_float2(rx, ry);
        }
    } else {
        outb[(size_t)n * PITCH_U + lane] = f2bf(rx) | (f2bf(ry) << 16);
    }
}

// ---------------- mega-kernel: whole pipeline, grid-size-agnostic ----------------

__global__ __launch_bounds__(256, 4) void mega(
    const float4* __restrict__ emb, const float* __restrict__ W1,
    const float* __restrict__ b1, const float* __restrict__ W2,
    const float* __restrict__ b2, const int* __restrict__ ids,
    const int* __restrict__ esrc, const int* __restrict__ edst,
    unsigned* __restrict__ h0b, unsigned* __restrict__ a1b, unsigned* __restrict__ gbu,
    ushort_t* __restrict__ W1t, ushort_t* __restrict__ W2t,
    int* __restrict__ deg, int* __restrict__ off, int* __restrict__ cursor,
    int* __restrict__ ssrc, int* __restrict__ bsum, int* __restrict__ bbase,
    float2* __restrict__ out) {
    cg::grid_group grid = cg::this_grid();
    const int P2 = 264;                                // H1s pitch (bf16)
    __shared__ alignas(16) char smem[64 * P2 * 2];     // 33.8 KB
    ushort_t* H1s = (ushort_t*)smem;
    int* ls = (int*)smem;

    int tid = threadIdx.x, lane = tid & 63, w = tid >> 6;
    int rl = lane & 15, kg = lane >> 4;
    int b = blockIdx.x;
    int G = gridDim.x;

    // ---- P1: count_deg | h0 gather | weight prep (independent, unit-partitioned) ----
    for (int u = b; u < 9591; u += G) {
        if (u < 3125) {
            int e = u * 256 + tid;                       // 3125*256 == N_EDGES
            atomicAdd(&deg[edst[e]], 1);
        } else if (u < 9375) {
            int i = (u - 3125) * 256 + tid;              // i = n*32+q, 6250*256 == N*32
            int n = i >> 5, q = i & 31;
            uint2 o = make_uint2(0u, 0u);
            if (q < 25) {
                float4 v = emb[(size_t)ids[n] * 25 + q];
                o.x = f2bf(v.x) | (f2bf(v.y) << 16);
                o.y = f2bf(v.z) | (f2bf(v.w) << 16);
            }
            ((uint2*)h0b)[i] = o;
        } else {
            int i = (u - 9375) * 256 + tid;              // 216*256 == 26624+28672
            if (i < 208 * 128) {
                int n = i >> 7, k = i & 127;
                float v = (n < HDIM && k < CDIM) ? W1[k * HDIM + n] : 0.f;
                W1t[i] = (ushort_t)f2bf(v);
            } else {
                int jj = i - 208 * 128;
                int n = jj >> 8, k = jj & 255;
                float v = (n < ODIM && k < HDIM) ? W2[k * ODIM + n] : 0.f;
                W2t[jj] = (ushort_t)f2bf(v);
            }
        }
    }
    grid.sync();

    // ---- P2a: per-chunk sums of deg (grid-stride over VCHUNKS) ----
    for (int chunk = b; chunk < VCHUNKS; chunk += G) {
        int start = chunk * CHUNK;
        int len = N_NODES - start;
        if (len > CHUNK) len = CHUNK;
        int v = (tid < len) ? deg[start + tid] : 0;
        ls[tid] = v;
        __syncthreads();
        for (int o = 128; o > 0; o >>= 1) {
            if (tid < o) ls[tid] += ls[tid + o];
            __syncthreads();
        }
        if (tid == 0) bsum[chunk] = ls[0];
        __syncthreads();
    }
    grid.sync();

    // ---- P2b: block 0 scans the VCHUNKS chunk sums -> bbase (exclusive) ----
    if (b == 0) {
        int s4[4];
        int s = 0;
#pragma unroll
        for (int i = 0; i < 4; ++i) { s4[i] = bsum[tid * 4 + i]; s += s4[i]; }
        ls[tid] = s;
        __syncthreads();
        for (int o = 1; o < 256; o <<= 1) {
            int v = (tid >= o) ? ls[tid - o] : 0;
            __syncthreads();
            ls[tid] += v;
            __syncthreads();
        }
        int run = (tid == 0) ? 0 : ls[tid - 1];
#pragma unroll
        for (int i = 0; i < 4; ++i) { bbase[tid * 4 + i] = run; run += s4[i]; }
    }
    grid.sync();

    // ---- P2c: per-chunk sequential offsets (grid-stride) ----
    for (int chunk = b; chunk < VCHUNKS; chunk += G) {
        int start = chunk * CHUNK;
        if (start >= N_NODES) continue;
        int len = N_NODES - start;
        if (len > CHUNK) len = CHUNK;
        if (tid < len) ls[tid] = deg[start + tid];
        __syncthreads();
        if (tid == 0) {
            int run = bbase[chunk];
            for (int i = 0; i < len; ++i) {
                off[start + i] = run;
                cursor[start + i] = run;
                run += ls[i];
            }
            if (start + len == N_NODES) off[N_NODES] = run;
        }
        __syncthreads();
    }
    grid.sync();

    // ---- P3: scatter edges into CSR slots ----
    for (int e = b * 256 + tid; e < N_EDGES; e += G * 256) {
        int p = atomicAdd(&cursor[edst[e]], 1);
        ssrc[p] = esrc[e];
    }
    grid.sync();

    // ---- P4: agg1 = segsum(h0[src]) -> a1b (bf16, pitch 256B) ----
    for (int n = b * 4 + w; n < N_NODES; n += G * 4) {
        agg_node<false>(n, lane, h0b, ssrc, off, nullptr, a1b, nullptr);
    }
    grid.sync();

    // ---- P5: g = relu(agg1 @ W1 + b1) @ W2 -> gb (bf16, pitch 256B) ----
    for (int tile = b; tile * 64 < N_NODES; tile += G) {
        int row0 = tile * 64;
        const ushort_t* Ab = (const ushort_t*)a1b;
        bf16x8 afr[4];
        size_t abase = (size_t)(row0 + w * 16 + rl) * 128;
#pragma unroll
        for (int k2 = 0; k2 < 4; ++k2)
            afr[k2] = *reinterpret_cast<const bf16x8*>(&Ab[abase + k2 * 32 + kg * 8]);
        // zero H1s pad cols 200..263
        for (int idx = tid; idx < 64 * 32; idx += 256) {
            int r = idx >> 5, c = idx & 31;
            ((unsigned*)&H1s[r * P2 + 200])[c] = 0;
        }
        // stage 1, tile-at-a-time
#pragma unroll
        for (int t = 0; t < 13; ++t) {
            f32x4 acc = (f32x4){0.f, 0.f, 0.f, 0.f};
#pragma unroll
            for (int k2 = 0; k2 < 4; ++k2) {
                bf16x8 bb = *reinterpret_cast<const bf16x8*>(&W1t[(t * 16 + rl) * 128 + k2 * 32 + kg * 8]);
                acc = __builtin_amdgcn_mfma_f32_16x16x32_bf16(afr[k2], bb, acc, 0, 0, 0);
            }
            int col = t * 16 + rl;
            if (col < HDIM) {
                float bv = b1[col];
#pragma unroll
                for (int i = 0; i < 4; ++i)
                    H1s[(w * 16 + kg * 4 + i) * P2 + col] = (ushort_t)f2bf(fmaxf(acc[i] + bv, 0.f));
            }
        }
        __syncthreads();
        // stage 2
        bf16x8 ha[8];
#pragma unroll
        for (int k2 = 0; k2 < 8; ++k2)
            ha[k2] = *reinterpret_cast<const bf16x8*>(&H1s[(w * 16 + rl) * P2 + k2 * 32 + kg * 8]);
#pragma unroll
        for (int t = 0; t < 7; ++t) {
            f32x4 acc = (f32x4){0.f, 0.f, 0.f, 0.f};
#pragma unroll
            for (int k2 = 0; k2 < 8; ++k2) {
                bf16x8 bb = *reinterpret_cast<const bf16x8*>(&W2t[(t * 16 + rl) * 256 + k2 * 32 + kg * 8]);
                acc = __builtin_amdgcn_mfma_f32_16x16x32_bf16(ha[k2], bb, acc, 0, 0, 0);
            }
            int col = t * 16 + rl;
#pragma unroll
            for (int i = 0; i < 4; ++i) {
                int row = row0 + w * 16 + kg * 4 + i;
                if (row < N_NODES) {
                    float v = (col < ODIM) ? acc[i] : 0.f;
                    ((ushort_t*)gbu)[(size_t)row * 128 + col] = (ushort_t)f2bf(v);
                }
            }
        }
        for (int idx = tid; idx < 64 * 8; idx += 256) {
            int r = idx >> 3, c = idx & 7;
            int row = row0 + r;
            if (row < N_NODES) gbu[(size_t)row * PITCH_U + 56 + c] = 0;
        }
        __syncthreads();
    }
    grid.sync();

    // ---- P6: out = relu(segsum(g[src]) + b2) (fp32) ----
    for (int n = b * 4 + w; n < N_NODES; n += G * 4) {
        agg_node<true>(n, lane, gbu, ssrc, off, b2, nullptr, out);
    }
}

// ================= fallback path (proven R8 kernels) =================

__global__ void count_deg(const int* __restrict__ dst, int* __restrict__ deg) {
    int e = blockIdx.x * 256 + threadIdx.x;
    if (e < N_EDGES) atomicAdd(&deg[dst[e]], 1);
}

__global__ __launch_bounds__(1024) void scan_deg(const int* __restrict__ deg,
                                                 int* __restrict__ off,
                                                 int* __restrict__ cursor) {
    const int T = 1024;
    const int PER = 52;
    int t = threadIdx.x;
    int start = t * PER;
    const int4* deg4 = (const int4*)deg;
    int sum = 0;
    if (start + PER <= N_NODES) {
#pragma unroll
        for (int q = 0; q < PER / 4; ++q) {
            int4 v = deg4[start / 4 + q];
            sum += v.x + v.y + v.z + v.w;
        }
    } else {
        for (int i = start; i < N_NODES; ++i) sum += deg[i];
    }
    __shared__ int ls[T];
    ls[t] = sum;
    __syncthreads();
    for (int o = 1; o < T; o <<= 1) {
        int v = (t >= o) ? ls[t - o] : 0;
        __syncthreads();
        ls[t] += v;
        __syncthreads();
    }
    int run = (t == 0) ? 0 : ls[t - 1];
    if (start + PER <= N_NODES) {
        int4* off4 = (int4*)off;
        int4* cur4 = (int4*)cursor;
#pragma unroll
        for (int q = 0; q < PER / 4; ++q) {
            int4 v = deg4[start / 4 + q];
            int4 o;
            o.x = run; o.y = o.x + v.x; o.z = o.y + v.y; o.w = o.z + v.z;
            run = o.w + v.w;
            off4[start / 4 + q] = o;
            cur4[start / 4 + q] = o;
        }
    } else if (start <= N_NODES) {
        for (int i = start; i < N_NODES; ++i) {
            off[i] = run; cursor[i] = run; run += deg[i];
        }
        off[N_NODES] = run;
    }
}

__global__ __launch_bounds__(256) void scatter_gather_prep(
    const int* __restrict__ esrc, const int* __restrict__ edst,
    int* __restrict__ cursor, int* __restrict__ ssrc,
    const float4* __restrict__ emb, const int* __restrict__ ids, uint2* __restrict__ h0,
    const float* __restrict__ W1, const float* __restrict__ W2,
    ushort_t* __restrict__ W1t, ushort_t* __restrict__ W2t) {
    int b = blockIdx.x;
    if (b < 3125) {
        int e = b * 256 + threadIdx.x;
        if (e < N_EDGES) {
            int p = atomicAdd(&cursor[edst[e]], 1);
            ssrc[p] = esrc[e];
        }
    } else if (b < 9375) {
        int i = (b - 3125) * 256 + threadIdx.x;
        const int TOT = N_NODES * 32;
        if (i < TOT) {
            int n = i >> 5, q = i & 31;
            uint2 o = make_uint2(0u, 0u);
            if (q < 25) {
                float4 v = emb[(size_t)ids[n] * 25 + q];
                o.x = f2bf(v.x) | (f2bf(v.y) << 16);
                o.y = f2bf(v.z) | (f2bf(v.w) << 16);
            }
            h0[i] = o;
        }
    } else {
        int i = (b - 9375) * 256 + threadIdx.x;
        if (i < 208 * 128) {
            int n = i >> 7, k = i & 127;
            float v = (n < HDIM && k < CDIM) ? W1[k * HDIM + n] : 0.f;
            W1t[i] = (ushort_t)f2bf(v);
        } else {
            int j = i - 208 * 128;
            if (j < 112 * 256) {
                int n = j >> 8, k = j & 255;
                float v = (n < ODIM && k < HDIM) ? W2[k * ODIM + n] : 0.f;
                W2t[j] = (ushort_t)f2bf(v);
            }
        }
    }
}

template <bool BIAS_RELU>
__global__ __launch_bounds__(256) void agg_bf16(const unsigned* __restrict__ hb,
                                                const int* __restrict__ ssrc,
                                                const int* __restrict__ off,
                                                const float* __restrict__ bias,
                                                unsigned* __restrict__ outb,
                                                float2* __restrict__ outf) {
    int wave = threadIdx.x >> 6;
    int lane = threadIdx.x & 63;
    int n = blockIdx.x * 4 + wave;
    if (n >= N_NODES) return;
    agg_node<BIAS_RELU>(n, lane, hb, ssrc, off, bias, outb, outf);
}

__global__ __launch_bounds__(256) void gemm_fused(const ushort_t* __restrict__ Ab,
                                                  const ushort_t* __restrict__ W1t,
                                                  const float* __restrict__ b1,
                                                  const ushort_t* __restrict__ W2t,
                                                  ushort_t* __restrict__ gb) {
    const int P2 = 264;
    __shared__ alignas(16) ushort_t H1s[64 * P2];
    int tid = threadIdx.x, lane = tid & 63, w = tid >> 6;
    int rl = lane & 15, kg = lane >> 4;
    int row0 = blockIdx.x * 64;
    size_t abase = ((size_t)(row0 + w * 16 + rl)) * 128;
    f32x4 acc1[13];
#pragma unroll
    for (int t = 0; t < 13; ++t) acc1[t] = (f32x4){0.f, 0.f, 0.f, 0.f};
#pragma unroll
    for (int k2 = 0; k2 < 4; ++k2) {
        bf16x8 a = *reinterpret_cast<const bf16x8*>(&Ab[abase + k2 * 32 + kg * 8]);
#pragma unroll
        for (int t = 0; t < 13; ++t) {
            bf16x8 b = *reinterpret_cast<const bf16x8*>(&W1t[(t * 16 + rl) * 128 + k2 * 32 + kg * 8]);
            acc1[t] = __builtin_amdgcn_mfma_f32_16x16x32_bf16(a, b, acc1[t], 0, 0, 0);
        }
    }
    for (int idx = tid; idx < 64 * 32; idx += 256) {
        int r = idx >> 5, c = idx & 31;
        ((unsigned*)&H1s[r * P2 + 200])[c] = 0;
    }
#pragma unroll
    for (int t = 0; t < 13; ++t) {
        int col = t * 16 + rl;
        if (col < HDIM) {
            float bv = b1[col];
#pragma unroll
            for (int i = 0; i < 4; ++i) {
                int r = w * 16 + kg * 4 + i;
                H1s[r * P2 + col] = (ushort_t)f2bf(fmaxf(acc1[t][i] + bv, 0.f));
            }
        }
    }
    __syncthreads();
    f32x4 acc2[7];
#pragma unroll
    for (int t = 0; t < 7; ++t) acc2[t] = (f32x4){0.f, 0.f, 0.f, 0.f};
#pragma unroll
    for (int k2 = 0; k2 < 8; ++k2) {
        bf16x8 a = *reinterpret_cast<const bf16x8*>(&H1s[(w * 16 + rl) * P2 + k2 * 32 + kg * 8]);
#pragma unroll
        for (int t = 0; t < 7; ++t) {
            bf16x8 b = *reinterpret_cast<const bf16x8*>(&W2t[(t * 16 + rl) * 256 + k2 * 32 + kg * 8]);
            acc2[t] = __builtin_amdgcn_mfma_f32_16x16x32_bf16(a, b, acc2[t], 0, 0, 0);
        }
    }
#pragma unroll
    for (int t = 0; t < 7; ++t) {
        int col = t * 16 + rl;
#pragma unroll
        for (int i = 0; i < 4; ++i) {
            int row = row0 + w * 16 + kg * 4 + i;
            if (row < N_NODES) {
                float v = (col < ODIM) ? acc2[t][i] : 0.f;
                gb[(size_t)row * 128 + col] = (ushort_t)f2bf(v);
            }
        }
    }
    unsigned* gbu = (unsigned*)gb;
    for (int idx = tid; idx < 64 * 8; idx += 256) {
        int r = idx >> 3, c = idx & 7;
        int row = row0 + r;
        if (row < N_NODES) gbu[(size_t)row * PITCH_U + 56 + c] = 0;
    }
}

// ---------------- launch ----------------

extern "C" void kernel_launch(void* const* d_in, const int* in_sizes, int n_in,
                              void* d_out, int out_size, void* d_ws, size_t ws_size,
                              hipStream_t stream) {
    const float4* emb = (const float4*)d_in[0];
    const float* W1  = (const float*)d_in[1];
    const float* b1  = (const float*)d_in[2];
    const float* W2  = (const float*)d_in[3];
    const float* b2  = (const float*)d_in[4];
    const int* ids   = (const int*)d_in[5];
    const int* esrc  = (const int*)d_in[6];
    const int* edst  = (const int*)d_in[7];
    float2* out = (float2*)d_out;

    // workspace layout (~43 MB)
    unsigned* h0b = (unsigned*)d_ws;                    // [N][64] uints (bf16 pairs)
    unsigned* a1b = h0b + (size_t)N_NODES * PITCH_U;
    unsigned* gbu = a1b + (size_t)N_NODES * PITCH_U;
    ushort_t* W1t = (ushort_t*)(gbu + (size_t)N_NODES * PITCH_U);  // [208][128]
    ushort_t* W2t = W1t + 208 * 128;                    // [112][256]
    int* deg    = (int*)(W2t + 112 * 256);
    int* off    = deg + N_NODES;
    int* cursor = off + (N_NODES + 1);
    int* ssrc   = cursor + N_NODES;                     // 800K ints
    int* bsum   = ssrc + N_EDGES;                       // VCHUNKS
    int* bbase  = bsum + VCHUNKS;                       // VCHUNKS

    hipMemsetAsync(deg, 0, N_NODES * sizeof(int), stream);

    // size the cooperative grid from the runtime's occupancy answer
    int dev = 0, cus = 0, bpc = 0;
    hipGetDevice(&dev);
    hipDeviceGetAttribute(&cus, hipDeviceAttributeMultiprocessorCount, dev);
    hipError_t qe = hipOccupancyMaxActiveBlocksPerMultiprocessor(&bpc, mega, BLK, 0);

    hipError_t le = hipErrorUnknown;
    if (qe == hipSuccess && bpc >= 1 && cus >= 1) {
        long g = (long)bpc * (long)cus;
        if (g >= 256) {
            int grid = (int)(g > 2048 ? 2048 : g);
            void* args[] = {&emb, &W1, &b1, &W2, &b2, &ids, &esrc, &edst,
                            &h0b, &a1b, &gbu, &W1t, &W2t,
                            &deg, &off, &cursor, &ssrc, &bsum, &bbase, &out};
            le = hipLaunchCooperativeKernel((const void*)mega, dim3(grid), dim3(BLK),
                                            args, 0, stream);
        }
    }

    if (le != hipSuccess) {
        // fallback: proven R8 multi-kernel path (identical math)
        count_deg<<<(N_EDGES + 255) / 256, 256, 0, stream>>>(edst, deg);
        scan_deg<<<1, 1024, 0, stream>>>(deg, off, cursor);
        scatter_gather_prep<<<9591, 256, 0, stream>>>(esrc, edst, cursor, ssrc,
                                                      emb, ids, (uint2*)h0b,
                                                      W1, W2, W1t, W2t);
        agg_bf16<false><<<N_NODES / 4, 256, 0, stream>>>(h0b, ssrc, off,
                                                         nullptr, a1b, nullptr);
        gemm_fused<<<(N_NODES + 63) / 64, 256, 0, stream>>>((const ushort_t*)a1b, W1t, b1,
                                                            W2t, (ushort_t*)gbu);
        agg_bf16<true><<<N_NODES / 4, 256, 0, stream>>>(gbu, ssrc, off,
                                                        b2, nullptr, out);
    }
}

// Round 11
// 199.467 us; speedup vs baseline: 3.8026x; 3.8026x over previous
//
#include <hip/hip_runtime.h>

#define N_NODES 50000
#define N_EDGES 800000
#define CDIM 100
#define HDIM 200
#define ODIM 100

#define PITCH_U 64   // node rows: 128 bf16 = 64 uints = 256 B

typedef __bf16 bf16x8 __attribute__((ext_vector_type(8)));
typedef float f32x4 __attribute__((ext_vector_type(4)));
typedef unsigned short ushort_t;

__device__ __forceinline__ unsigned f2bf(float f) {
    unsigned u = __float_as_uint(f);
    u = (u + 0x7FFFu + ((u >> 16) & 1u)) >> 16;
    return u;  // low 16 bits valid
}
__device__ __forceinline__ float bflo(unsigned u) { return __uint_as_float(u << 16); }
__device__ __forceinline__ float bfhi(unsigned u) { return __uint_as_float(u & 0xFFFF0000u); }

// ---------------- CSR build ----------------
// count_rank: deg histogram AND per-edge rank within its dst bucket (one atomic pass).

__global__ void count_rank(const int* __restrict__ dst, int* __restrict__ deg,
                           int* __restrict__ rank) {
    int e = blockIdx.x * 256 + threadIdx.x;
    if (e < N_EDGES) rank[e] = atomicAdd(&deg[dst[e]], 1);
}

__global__ __launch_bounds__(1024) void scan_deg(const int* __restrict__ deg,
                                                 int* __restrict__ off) {
    const int T = 1024;
    const int PER = 52;  // 13 int4s; 962 threads cover 50000
    int t = threadIdx.x;
    int start = t * PER;
    const int4* deg4 = (const int4*)deg;

    int sum = 0;
    if (start + PER <= N_NODES) {
#pragma unroll
        for (int q = 0; q < PER / 4; ++q) {
            int4 v = deg4[start / 4 + q];
            sum += v.x + v.y + v.z + v.w;
        }
    } else {
        for (int i = start; i < N_NODES; ++i) sum += deg[i];
    }

    __shared__ int ls[T];
    ls[t] = sum;
    __syncthreads();
    for (int o = 1; o < T; o <<= 1) {
        int v = (t >= o) ? ls[t - o] : 0;
        __syncthreads();
        ls[t] += v;
        __syncthreads();
    }
    int run = (t == 0) ? 0 : ls[t - 1];

    if (start + PER <= N_NODES) {
        int4* off4 = (int4*)off;
#pragma unroll
        for (int q = 0; q < PER / 4; ++q) {
            int4 v = deg4[start / 4 + q];
            int4 o;
            o.x = run;
            o.y = o.x + v.x;
            o.z = o.y + v.y;
            o.w = o.z + v.z;
            run = o.w + v.w;
            off4[start / 4 + q] = o;
        }
    } else if (start <= N_NODES) {
        for (int i = start; i < N_NODES; ++i) {
            off[i] = run;
            run += deg[i];
        }
        off[N_NODES] = run;
    }
}

// ---------------- fused independent stage: scatter | gather | weight-prep ----------
// blocks [0,3125): scatter edges into CSR slots (NO atomics: slot = off[dst] + rank)
// blocks [3125,9375): h0 = bf16(emb[ids]) into pitch-256B rows (pad cols zeroed)
// blocks [9375,9591): W1t[208][128] <- bf16(W1^T); W2t[112][256] <- bf16(W2^T)

__global__ __launch_bounds__(256) void scatter_gather_prep(
    const int* __restrict__ esrc, const int* __restrict__ edst,
    const int* __restrict__ off, const int* __restrict__ rank, int* __restrict__ ssrc,
    const float4* __restrict__ emb, const int* __restrict__ ids, uint2* __restrict__ h0,
    const float* __restrict__ W1, const float* __restrict__ W2,
    ushort_t* __restrict__ W1t, ushort_t* __restrict__ W2t) {
    int b = blockIdx.x;
    if (b < 3125) {
        int e = b * 256 + threadIdx.x;
        if (e < N_EDGES) {
            int p = off[edst[e]] + rank[e];   // off: 200KB, L2-resident -> cheap gather
            ssrc[p] = esrc[e];
        }
    } else if (b < 9375) {
        int i = (b - 3125) * 256 + threadIdx.x;  // i = n*32+q (32 uint2 per row)
        const int TOT = N_NODES * 32;            // 1.6M uint2
        if (i < TOT) {
            int n = i >> 5, q = i & 31;
            uint2 o = make_uint2(0u, 0u);
            if (q < 25) {
                float4 v = emb[(size_t)ids[n] * 25 + q];
                o.x = f2bf(v.x) | (f2bf(v.y) << 16);
                o.y = f2bf(v.z) | (f2bf(v.w) << 16);
            }
            h0[i] = o;
        }
    } else {
        int i = (b - 9375) * 256 + threadIdx.x;
        if (i < 208 * 128) {
            int n = i >> 7, k = i & 127;
            float v = (n < HDIM && k < CDIM) ? W1[k * HDIM + n] : 0.f;
            W1t[i] = (ushort_t)f2bf(v);
        } else {
            int j = i - 208 * 128;
            if (j < 112 * 256) {
                int n = j >> 8, k = j & 255;
                float v = (n < ODIM && k < HDIM) ? W2[k * ODIM + n] : 0.f;
                W2t[j] = (ushort_t)f2bf(v);
            }
        }
    }
}

// ---------------- CSR aggregation over pitch-256B bf16 rows, fp32 accum ----------
// 1 wave/node, 64 lanes (lanes 50..63 carry pad zeros); 8-deep unconditional ILP.
// !BIAS_RELU: write packed bf16 pitch-64-uint row (incl. zero pads).
// BIAS_RELU: +bias, relu, write fp32 dense [N][100] (lanes < 50).

template <bool BIAS_RELU>
__global__ __launch_bounds__(256) void agg_bf16(const unsigned* __restrict__ hb,
                                                const int* __restrict__ ssrc,
                                                const int* __restrict__ off,
                                                const float* __restrict__ bias,
                                                unsigned* __restrict__ outb,
                                                float2* __restrict__ outf) {
    int wave = threadIdx.x >> 6;
    int lane = threadIdx.x & 63;
    int n = blockIdx.x * 4 + wave;
    if (n >= N_NODES) return;
    int s0 = off[n], s1 = off[n + 1];

    float2 a0 = {0.f, 0.f}, a1 = {0.f, 0.f}, a2 = {0.f, 0.f}, a3 = {0.f, 0.f};
    int j = s0;
    for (; j + 7 < s1; j += 8) {
        int r0 = ssrc[j],     r1 = ssrc[j + 1], r2 = ssrc[j + 2], r3 = ssrc[j + 3];
        int r4 = ssrc[j + 4], r5 = ssrc[j + 5], r6 = ssrc[j + 6], r7 = ssrc[j + 7];
        unsigned u0 = hb[(size_t)r0 * PITCH_U + lane];
        unsigned u1 = hb[(size_t)r1 * PITCH_U + lane];
        unsigned u2 = hb[(size_t)r2 * PITCH_U + lane];
        unsigned u3 = hb[(size_t)r3 * PITCH_U + lane];
        unsigned u4 = hb[(size_t)r4 * PITCH_U + lane];
        unsigned u5 = hb[(size_t)r5 * PITCH_U + lane];
        unsigned u6 = hb[(size_t)r6 * PITCH_U + lane];
        unsigned u7 = hb[(size_t)r7 * PITCH_U + lane];
        a0.x += bflo(u0); a0.y += bfhi(u0);
        a1.x += bflo(u1); a1.y += bfhi(u1);
        a2.x += bflo(u2); a2.y += bfhi(u2);
        a3.x += bflo(u3); a3.y += bfhi(u3);
        a0.x += bflo(u4); a0.y += bfhi(u4);
        a1.x += bflo(u5); a1.y += bfhi(u5);
        a2.x += bflo(u6); a2.y += bfhi(u6);
        a3.x += bflo(u7); a3.y += bfhi(u7);
    }
    for (; j + 3 < s1; j += 4) {
        int r0 = ssrc[j], r1 = ssrc[j + 1], r2 = ssrc[j + 2], r3 = ssrc[j + 3];
        unsigned u0 = hb[(size_t)r0 * PITCH_U + lane];
        unsigned u1 = hb[(size_t)r1 * PITCH_U + lane];
        unsigned u2 = hb[(size_t)r2 * PITCH_U + lane];
        unsigned u3 = hb[(size_t)r3 * PITCH_U + lane];
        a0.x += bflo(u0); a0.y += bfhi(u0);
        a1.x += bflo(u1); a1.y += bfhi(u1);
        a2.x += bflo(u2); a2.y += bfhi(u2);
        a3.x += bflo(u3); a3.y += bfhi(u3);
    }
    {
        int rem = s1 - j;
        if (rem > 0) { unsigned u = hb[(size_t)ssrc[j] * PITCH_U + lane];     a0.x += bflo(u); a0.y += bfhi(u); }
        if (rem > 1) { unsigned u = hb[(size_t)ssrc[j + 1] * PITCH_U + lane]; a1.x += bflo(u); a1.y += bfhi(u); }
        if (rem > 2) { unsigned u = hb[(size_t)ssrc[j + 2] * PITCH_U + lane]; a2.x += bflo(u); a2.y += bfhi(u); }
    }
    float rx = (a0.x + a1.x) + (a2.x + a3.x);
    float ry = (a0.y + a1.y) + (a2.y + a3.y);
    if (BIAS_RELU) {
        if (lane < 50) {
            rx = fmaxf(rx + bias[2 * lane], 0.f);
            ry = fmaxf(ry + bias[2 * lane + 1], 0.f);
            outf[(size_t)n * 50 + lane] = make_float2(rx, ry);
        }
    } else {
        outb[(size_t)n * PITCH_U + lane] = f2bf(rx) | (f2bf(ry) << 16);
    }
}

// ---------------- fused MLP: g = relu(A @ W1t^T + b1) @ W2t^T, all bf16 MFMA --------
// A: a1b [N][128] bf16 (pitch-256B, zero-padded). W1t [208][128], W2t [112][256].
// Block = 4 waves x 16 rows = 64 rows. Stage-1 A-frags read directly from global.
// h1 tile lives only in LDS. g out: pitch-256B rows, pad cols zeroed.

__global__ __launch_bounds__(256) void gemm_fused(const ushort_t* __restrict__ Ab,
                                                  const ushort_t* __restrict__ W1t,
                                                  const float* __restrict__ b1,
                                                  const ushort_t* __restrict__ W2t,
                                                  ushort_t* __restrict__ gb) {
    const int P2 = 264;  // H1s row pitch (bf16): 200 data + 56 zero + 8 slack
    __shared__ alignas(16) ushort_t H1s[64 * P2];  // 33.8 KB

    int tid = threadIdx.x, lane = tid & 63, w = tid >> 6;
    int rl = lane & 15, kg = lane >> 4;
    int row0 = blockIdx.x * 64;

    size_t abase = ((size_t)(row0 + w * 16 + rl)) * 128;
    f32x4 acc1[13];
#pragma unroll
    for (int t = 0; t < 13; ++t) acc1[t] = (f32x4){0.f, 0.f, 0.f, 0.f};
#pragma unroll
    for (int k2 = 0; k2 < 4; ++k2) {
        bf16x8 a = *reinterpret_cast<const bf16x8*>(&Ab[abase + k2 * 32 + kg * 8]);
#pragma unroll
        for (int t = 0; t < 13; ++t) {
            bf16x8 b = *reinterpret_cast<const bf16x8*>(&W1t[(t * 16 + rl) * 128 + k2 * 32 + kg * 8]);
            acc1[t] = __builtin_amdgcn_mfma_f32_16x16x32_bf16(a, b, acc1[t], 0, 0, 0);
        }
    }
    // zero pad cols 200..263
    for (int idx = tid; idx < 64 * 32; idx += 256) {
        int r = idx >> 5, c = idx & 31;
        ((unsigned*)&H1s[r * P2 + 200])[c] = 0;
    }
    // h1 = relu(acc1 + b1) -> bf16 LDS tile (D layout: col=lane&15, row=(lane>>4)*4+i)
#pragma unroll
    for (int t = 0; t < 13; ++t) {
        int col = t * 16 + rl;
        if (col < HDIM) {
            float bv = b1[col];
#pragma unroll
            for (int i = 0; i < 4; ++i) {
                int r = w * 16 + kg * 4 + i;
                H1s[r * P2 + col] = (ushort_t)f2bf(fmaxf(acc1[t][i] + bv, 0.f));
            }
        }
    }
    __syncthreads();

    f32x4 acc2[7];
#pragma unroll
    for (int t = 0; t < 7; ++t) acc2[t] = (f32x4){0.f, 0.f, 0.f, 0.f};
#pragma unroll
    for (int k2 = 0; k2 < 8; ++k2) {
        bf16x8 a = *reinterpret_cast<const bf16x8*>(&H1s[(w * 16 + rl) * P2 + k2 * 32 + kg * 8]);
#pragma unroll
        for (int t = 0; t < 7; ++t) {
            bf16x8 b = *reinterpret_cast<const bf16x8*>(&W2t[(t * 16 + rl) * 256 + k2 * 32 + kg * 8]);
            acc2[t] = __builtin_amdgcn_mfma_f32_16x16x32_bf16(a, b, acc2[t], 0, 0, 0);
        }
    }

#pragma unroll
    for (int t = 0; t < 7; ++t) {
        int col = t * 16 + rl;
#pragma unroll
        for (int i = 0; i < 4; ++i) {
            int row = row0 + w * 16 + kg * 4 + i;
            if (row < N_NODES) {
                float v = (col < ODIM) ? acc2[t][i] : 0.f;
                gb[(size_t)row * 128 + col] = (ushort_t)f2bf(v);
            }
        }
    }
    unsigned* gbu = (unsigned*)gb;
    for (int idx = tid; idx < 64 * 8; idx += 256) {
        int r = idx >> 3, c = idx & 7;
        int row = row0 + r;
        if (row < N_NODES) gbu[(size_t)row * PITCH_U + 56 + c] = 0;
    }
}

// ---------------- launch ----------------

extern "C" void kernel_launch(void* const* d_in, const int* in_sizes, int n_in,
                              void* d_out, int out_size, void* d_ws, size_t ws_size,
                              hipStream_t stream) {
    const float4* emb = (const float4*)d_in[0];
    const float* W1  = (const float*)d_in[1];
    const float* b1  = (const float*)d_in[2];
    const float* W2  = (const float*)d_in[3];
    const float* b2  = (const float*)d_in[4];
    const int* ids   = (const int*)d_in[5];
    const int* esrc  = (const int*)d_in[6];
    const int* edst  = (const int*)d_in[7];
    float2* out = (float2*)d_out;

    // workspace layout (~46 MB)
    unsigned* h0b = (unsigned*)d_ws;                    // [N][64] uints (bf16 pairs)
    unsigned* a1b = h0b + (size_t)N_NODES * PITCH_U;
    unsigned* gbu = a1b + (size_t)N_NODES * PITCH_U;
    ushort_t* W1t = (ushort_t*)(gbu + (size_t)N_NODES * PITCH_U);  // [208][128]
    ushort_t* W2t = W1t + 208 * 128;                    // [112][256]
    int* deg   = (int*)(W2t + 112 * 256);
    int* off   = deg + N_NODES;                         // N+1
    int* rank  = off + (N_NODES + 1);                   // 800K
    int* ssrc  = rank + N_EDGES;                        // 800K

    hipMemsetAsync(deg, 0, N_NODES * sizeof(int), stream);

    // CSR build: one atomic pass (deg + rank), scan, then atomic-free scatter
    count_rank<<<(N_EDGES + 255) / 256, 256, 0, stream>>>(edst, deg, rank);
    scan_deg<<<1, 1024, 0, stream>>>(deg, off);

    // scatter + gather + weight-prep (mutually independent) in one launch
    scatter_gather_prep<<<9591, 256, 0, stream>>>(esrc, edst, off, rank, ssrc,
                                                  emb, ids, (uint2*)h0b,
                                                  W1, W2, W1t, W2t);

    // agg1 = segsum(h0[src])  (bf16 pitch-256B out)
    agg_bf16<false><<<N_NODES / 4, 256, 0, stream>>>(h0b, ssrc, off,
                                                     nullptr, a1b, nullptr);
    // g = relu(agg1 @ W1 + b1) @ W2  (h1 never leaves LDS)
    gemm_fused<<<(N_NODES + 63) / 64, 256, 0, stream>>>((const ushort_t*)a1b, W1t, b1,
                                                        W2t, (ushort_t*)gbu);
    // out = relu(segsum(g[src]) + b2)  (fp32 out)
    agg_bf16<true><<<N_NODES / 4, 256, 0, stream>>>(gbu, ssrc, off,
                                                    b2, nullptr, out);
}